// Round 1
// baseline (1133.454 us; speedup 1.0000x reference)
//
#include <hip/hip_runtime.h>
#include <hip/hip_bf16.h>

#define N_ 8
#define C_ 32
#define H_ 64
#define W_ 64
#define HW_ (H_*W_)
#define NHW_ (N_*HW_)
#define INTER_ 64
#define BC_ 108
#define KS_ 7
#define K2_ (KS_*KS_)
#define NB_ 6
#define TB_ 18
#define OUT_ 64
#define DDIM_ (C_*NB_)   // 192

__inline__ __device__ float wave_reduce_sum(float v) {
    #pragma unroll
    for (int off = 32; off > 0; off >>= 1) v += __shfl_down(v, off);
    return v;
}

// y[n,co,h,w] = b[co] + sum_{ci,dy,dx} x[n,ci,h+dy-1,w+dx-1] * w[co,ci,dy,dx]
__global__ void k_conv3x3(const float* __restrict__ x, const float* __restrict__ w,
                          const float* __restrict__ b, float* __restrict__ y,
                          int Cin, int Cout) {
    int idx = blockIdx.x * blockDim.x + threadIdx.x;
    int total = N_ * Cout * HW_;
    if (idx >= total) return;
    int wp = idx & (W_ - 1);
    int hp = (idx >> 6) & (H_ - 1);
    int co = (idx / HW_) % Cout;
    int n  = idx / (HW_ * Cout);

    float acc = b[co];
    const float* xbase = x + (size_t)n * Cin * HW_;
    const float* wbase = w + (size_t)co * Cin * 9;
    for (int ci = 0; ci < Cin; ci++) {
        const float* xp = xbase + ci * HW_;
        const float* wp9 = wbase + ci * 9;
        #pragma unroll
        for (int dy = 0; dy < 3; dy++) {
            int hy = hp + dy - 1;
            if (hy < 0 || hy >= H_) continue;
            const float* xr = xp + hy * W_;
            #pragma unroll
            for (int dx = 0; dx < 3; dx++) {
                int wx = wp + dx - 1;
                if (wx < 0 || wx >= W_) continue;
                acc += xr[wx] * wp9[dy * 3 + dx];
            }
        }
    }
    y[idx] = acc;
}

// one block per channel: scale = g*rsqrt(var+eps), shift = b - mu*scale
__global__ void k_bnstats(const float* __restrict__ y, const float* __restrict__ g,
                          const float* __restrict__ bb, float* __restrict__ scale,
                          float* __restrict__ shift, int Cout) {
    int c = blockIdx.x;
    float s = 0.f, s2 = 0.f;
    for (int i = threadIdx.x; i < NHW_; i += blockDim.x) {
        int n = i >> 12;          // HW_=4096
        int p = i & 4095;
        float v = y[((size_t)(n * Cout + c)) * HW_ + p];
        s += v; s2 += v * v;
    }
    s = wave_reduce_sum(s);
    s2 = wave_reduce_sum(s2);
    __shared__ float sm[8];
    int wid = threadIdx.x >> 6, lane = threadIdx.x & 63;
    if (lane == 0) { sm[wid] = s; sm[4 + wid] = s2; }
    __syncthreads();
    if (threadIdx.x == 0) {
        float ts  = sm[0] + sm[1] + sm[2] + sm[3];
        float ts2 = sm[4] + sm[5] + sm[6] + sm[7];
        float mu  = ts / (float)NHW_;
        float var = ts2 / (float)NHW_ - mu * mu;
        float sc  = g[c] * rsqrtf(var + 1e-5f);
        scale[c] = sc;
        shift[c] = bb[c] - mu * sc;
    }
}

// y = tanh(y*scale[c]+shift[c]) in place
__global__ void k_bnact(float* __restrict__ y, const float* __restrict__ scale,
                        const float* __restrict__ shift, int Cout) {
    int idx = blockIdx.x * blockDim.x + threadIdx.x;
    int total = N_ * Cout * HW_;
    if (idx >= total) return;
    int c = (idx >> 12) % Cout;
    y[idx] = tanhf(y[idx] * scale[c] + shift[c]);
}

// one block (256 thr) per pixel
__global__ void k_final(const float* __restrict__ x, const float* __restrict__ coef,
                        const float* __restrict__ bases, const float* __restrict__ out_w,
                        const float* __restrict__ out_b, float* __restrict__ out) {
    __shared__ float s_coef[BC_];          // 108
    __shared__ float s_atoms[K2_ * NB_];   // 294, layout [k*NB+m]
    __shared__ float s_patch[C_ * K2_];    // 1568, layout [c*49+k]
    __shared__ float s_bout[DDIM_];        // 192, layout d=c*NB+m
    __shared__ float s_part[4][OUT_];

    int pix = blockIdx.x;
    int wp = pix & (W_ - 1);
    int hp = (pix >> 6) & (H_ - 1);
    int n  = pix >> 12;
    int t = threadIdx.x;

    // stage coef for this pixel (gather across 108 channels)
    for (int i = t; i < BC_; i += 256)
        s_coef[i] = coef[((size_t)(n * BC_ + i)) * HW_ + hp * W_ + wp];
    __syncthreads();

    // atoms[k,m] = sum_t coef[m*TB+t] * bases[t,k]
    for (int i = t; i < K2_ * NB_; i += 256) {
        int k = i / NB_, m = i % NB_;
        float a = 0.f;
        #pragma unroll
        for (int tt = 0; tt < TB_; tt++)
            a += s_coef[m * TB_ + tt] * bases[tt * K2_ + k];
        s_atoms[i] = a;
    }
    // stage 7x7 zero-padded patch, channel-major (c,ky,kx)
    for (int i = t; i < C_ * K2_; i += 256) {
        int c = i / K2_, k = i % K2_;
        int ky = k / KS_, kx = k % KS_;
        int hy = hp + ky - 3, wx = wp + kx - 3;
        float v = 0.f;
        if (hy >= 0 && hy < H_ && wx >= 0 && wx < W_)
            v = x[((size_t)(n * C_ + c)) * HW_ + hy * W_ + wx];
        s_patch[i] = v;
    }
    __syncthreads();

    // bases_out[c,m] = sum_k patch[c,k] * atoms[k,m]
    for (int i = t; i < DDIM_; i += 256) {
        int c = i / NB_, m = i % NB_;
        float a = 0.f;
        #pragma unroll
        for (int k = 0; k < K2_; k++)
            a += s_patch[c * K2_ + k] * s_atoms[k * NB_ + m];
        s_bout[i] = a;
    }
    __syncthreads();

    // out[o] = out_b[o] + sum_d bases_out[d] * out_w[o,d]  (split over 4 groups)
    {
        int o = t & 63, grp = t >> 6;
        float a = 0.f;
        #pragma unroll
        for (int d = grp * 48; d < grp * 48 + 48; d++)
            a += s_bout[d] * out_w[o * DDIM_ + d];
        s_part[grp][o] = a;
    }
    __syncthreads();
    if (t < OUT_) {
        float r = out_b[t] + s_part[0][t] + s_part[1][t] + s_part[2][t] + s_part[3][t];
        out[((size_t)(n * OUT_ + t)) * HW_ + hp * W_ + wp] = r;
    }
}

extern "C" void kernel_launch(void* const* d_in, const int* in_sizes, int n_in,
                              void* d_out, int out_size, void* d_ws, size_t ws_size,
                              hipStream_t stream) {
    const float* x       = (const float*)d_in[0];
    const float* conv1_w = (const float*)d_in[1];
    const float* conv1_b = (const float*)d_in[2];
    const float* bn1_g   = (const float*)d_in[3];
    const float* bn1_b   = (const float*)d_in[4];
    const float* conv2_w = (const float*)d_in[5];
    const float* conv2_b = (const float*)d_in[6];
    const float* bn2_g   = (const float*)d_in[7];
    const float* bn2_b   = (const float*)d_in[8];
    const float* bases   = (const float*)d_in[9];
    const float* out_w   = (const float*)d_in[10];
    const float* out_b   = (const float*)d_in[11];
    float* out = (float*)d_out;

    float* y1  = (float*)d_ws;                 // N*INTER*HW = 2,097,152
    float* y2  = y1 + (size_t)N_ * INTER_ * HW_; // N*BC*HW = 3,538,944
    float* sc1 = y2 + (size_t)N_ * BC_ * HW_;
    float* sh1 = sc1 + INTER_;
    float* sc2 = sh1 + INTER_;
    float* sh2 = sc2 + BC_;

    int tot1 = N_ * INTER_ * HW_;
    int tot2 = N_ * BC_ * HW_;

    k_conv3x3<<<(tot1 + 255) / 256, 256, 0, stream>>>(x, conv1_w, conv1_b, y1, C_, INTER_);
    k_bnstats<<<INTER_, 256, 0, stream>>>(y1, bn1_g, bn1_b, sc1, sh1, INTER_);
    k_bnact<<<(tot1 + 255) / 256, 256, 0, stream>>>(y1, sc1, sh1, INTER_);

    k_conv3x3<<<(tot2 + 255) / 256, 256, 0, stream>>>(y1, conv2_w, conv2_b, y2, INTER_, BC_);
    k_bnstats<<<BC_, 256, 0, stream>>>(y2, bn2_g, bn2_b, sc2, sh2, BC_);
    k_bnact<<<(tot2 + 255) / 256, 256, 0, stream>>>(y2, sc2, sh2, BC_);

    k_final<<<NHW_, 256, 0, stream>>>(x, y2, bases, out_w, out_b, out);
}

// Round 2
// 573.814 us; speedup vs baseline: 1.9753x; 1.9753x over previous
//
#include <hip/hip_runtime.h>
#include <hip/hip_bf16.h>

#define N_ 8
#define C_ 32
#define H_ 64
#define W_ 64
#define HW_ (H_*W_)
#define NHW_ (N_*HW_)
#define INTER_ 64
#define BC_ 108
#define KS_ 7
#define K2_ (KS_*KS_)
#define NB_ 6
#define TB_ 18
#define OUT_ 64
#define DDIM_ (C_*NB_)   // 192

__inline__ __device__ float wave_reduce_sum(float v) {
    #pragma unroll
    for (int off = 32; off > 0; off >>= 1) v += __shfl_down(v, off);
    return v;
}

// Tiled direct 3x3 conv, pad=1.
// Block tile: 16 co x 4 rows x 64 cols. Thread: 2 co x 1 row x 8 cols.
// x staged in LDS per 8-ci chunk with halo; weights staged padded for b128.
template<int CIN, int COUT>
__global__ __launch_bounds__(256) void k_conv_tiled(const float* __restrict__ x,
                                                    const float* __restrict__ w,
                                                    const float* __restrict__ b,
                                                    float* __restrict__ y) {
    constexpr int CO_T = 16, ROWS = 4, CI_CH = 8;
    constexpr int CO_TILES = (COUT + CO_T - 1) / CO_T;

    __shared__ float sx[CI_CH][ROWS + 2][68];   // phys col p -> wx = p-1; stride 68 (16B-aligned rows)
    __shared__ float sw[CO_T][CI_CH][12];       // 9 weights padded to 12

    int bid = blockIdx.x;
    int cot = bid % CO_TILES;
    int ht  = (bid / CO_TILES) % (H_ / ROWS);
    int n   = bid / (CO_TILES * (H_ / ROWS));
    int h0  = ht * ROWS;
    int co0 = cot * CO_T;

    int t   = threadIdx.x;
    int w8  = (t & 7) * 8;        // col base of this thread's 8 outputs
    int row = (t >> 3) & 3;       // output row within tile
    int cog = t >> 5;             // 0..7 -> co pair

    float acc[2][8];
    #pragma unroll
    for (int o = 0; o < 2; o++)
        #pragma unroll
        for (int j = 0; j < 8; j++) acc[o][j] = 0.f;

    for (int cc = 0; cc < CIN; cc += CI_CH) {
        // stage x: 8 ci x 6 rows x 66 phys cols (wx = -1..64), zero-padded borders
        for (int i = t; i < CI_CH * 6 * 66; i += 256) {
            int col = i % 66;
            int rr  = (i / 66) % 6;
            int ci  = i / 396;
            int hy  = h0 + rr - 1;
            int wx  = col - 1;
            float v = 0.f;
            if (hy >= 0 && hy < H_ && wx >= 0 && wx < W_)
                v = x[(((size_t)n * CIN + cc + ci) * HW_) + hy * W_ + wx];
            sx[ci][rr][col] = v;
        }
        // stage weights: 16 co x 8 ci x 9 (pad 12)
        for (int i = t; i < CO_T * CI_CH * 9; i += 256) {
            int k  = i % 9;
            int ci = (i / 9) % CI_CH;
            int co = i / (9 * CI_CH);
            float v = 0.f;
            if (co0 + co < COUT)
                v = w[(((size_t)(co0 + co) * CIN) + cc + ci) * 9 + k];
            sw[co][ci][k] = v;
        }
        __syncthreads();

        #pragma unroll
        for (int ci = 0; ci < CI_CH; ci++) {
            // load x neighborhood: 3 rows x 10 cols, vectorized
            float xr[3][10];
            #pragma unroll
            for (int r = 0; r < 3; r++) {
                const float* base = &sx[ci][row + r][w8];
                float4 a = *(const float4*)base;
                float4 bq = *(const float4*)(base + 4);
                float2 cq = *(const float2*)(base + 8);
                xr[r][0] = a.x;  xr[r][1] = a.y;  xr[r][2] = a.z;  xr[r][3] = a.w;
                xr[r][4] = bq.x; xr[r][5] = bq.y; xr[r][6] = bq.z; xr[r][7] = bq.w;
                xr[r][8] = cq.x; xr[r][9] = cq.y;
            }
            #pragma unroll
            for (int o = 0; o < 2; o++) {
                const float* wb = &sw[cog * 2 + o][ci][0];
                float4 w0 = *(const float4*)wb;
                float4 w1 = *(const float4*)(wb + 4);
                float  w8v = wb[8];
                float wreg[9] = {w0.x, w0.y, w0.z, w0.w, w1.x, w1.y, w1.z, w1.w, w8v};
                #pragma unroll
                for (int r = 0; r < 3; r++)
                    #pragma unroll
                    for (int k = 0; k < 3; k++) {
                        float wv = wreg[r * 3 + k];
                        #pragma unroll
                        for (int j = 0; j < 8; j++)
                            acc[o][j] += xr[r][j + k] * wv;
                    }
            }
        }
        __syncthreads();
    }

    #pragma unroll
    for (int o = 0; o < 2; o++) {
        int co = co0 + cog * 2 + o;
        if (co < COUT) {
            float bb = b[co];
            float* yp = &y[(((size_t)n * COUT + co) * HW_) + (h0 + row) * W_ + w8];
            float4 v0 = make_float4(acc[o][0] + bb, acc[o][1] + bb, acc[o][2] + bb, acc[o][3] + bb);
            float4 v1 = make_float4(acc[o][4] + bb, acc[o][5] + bb, acc[o][6] + bb, acc[o][7] + bb);
            *(float4*)yp = v0;
            *(float4*)(yp + 4) = v1;
        }
    }
}

// one block per channel: scale = g*rsqrt(var+eps), shift = b - mu*scale
__global__ void k_bnstats(const float* __restrict__ y, const float* __restrict__ g,
                          const float* __restrict__ bb, float* __restrict__ scale,
                          float* __restrict__ shift, int Cout) {
    int c = blockIdx.x;
    float s = 0.f, s2 = 0.f;
    for (int i = threadIdx.x; i < NHW_; i += blockDim.x) {
        int n = i >> 12;          // HW_=4096
        int p = i & 4095;
        float v = y[((size_t)(n * Cout + c)) * HW_ + p];
        s += v; s2 += v * v;
    }
    s = wave_reduce_sum(s);
    s2 = wave_reduce_sum(s2);
    __shared__ float sm[16];
    int wid = threadIdx.x >> 6, lane = threadIdx.x & 63;
    if (lane == 0) { sm[wid] = s; sm[8 + wid] = s2; }
    __syncthreads();
    if (threadIdx.x == 0) {
        float ts = 0.f, ts2 = 0.f;
        for (int i = 0; i < (int)(blockDim.x >> 6); i++) { ts += sm[i]; ts2 += sm[8 + i]; }
        float mu  = ts / (float)NHW_;
        float var = ts2 / (float)NHW_ - mu * mu;
        float sc  = g[c] * rsqrtf(var + 1e-5f);
        scale[c] = sc;
        shift[c] = bb[c] - mu * sc;
    }
}

// y = tanh(y*scale[c]+shift[c]) in place
__global__ void k_bnact(float* __restrict__ y, const float* __restrict__ scale,
                        const float* __restrict__ shift, int Cout) {
    int idx = blockIdx.x * blockDim.x + threadIdx.x;
    int total = N_ * Cout * HW_;
    if (idx >= total) return;
    int c = (idx >> 12) % Cout;
    y[idx] = tanhf(y[idx] * scale[c] + shift[c]);
}

// one block (256 thr) per pixel
__global__ void k_final(const float* __restrict__ x, const float* __restrict__ coef,
                        const float* __restrict__ bases, const float* __restrict__ out_w,
                        const float* __restrict__ out_b, float* __restrict__ out) {
    __shared__ float s_coef[BC_];          // 108
    __shared__ float s_atoms[K2_ * NB_];   // 294, layout [k*NB+m]
    __shared__ float s_patch[C_ * K2_];    // 1568, layout [c*49+k]
    __shared__ float s_bout[DDIM_];        // 192, layout d=c*NB+m
    __shared__ float s_part[4][OUT_];

    int pix = blockIdx.x;
    int wp = pix & (W_ - 1);
    int hp = (pix >> 6) & (H_ - 1);
    int n  = pix >> 12;
    int t = threadIdx.x;

    for (int i = t; i < BC_; i += 256)
        s_coef[i] = coef[((size_t)(n * BC_ + i)) * HW_ + hp * W_ + wp];
    __syncthreads();

    for (int i = t; i < K2_ * NB_; i += 256) {
        int k = i / NB_, m = i % NB_;
        float a = 0.f;
        #pragma unroll
        for (int tt = 0; tt < TB_; tt++)
            a += s_coef[m * TB_ + tt] * bases[tt * K2_ + k];
        s_atoms[i] = a;
    }
    for (int i = t; i < C_ * K2_; i += 256) {
        int c = i / K2_, k = i % K2_;
        int ky = k / KS_, kx = k % KS_;
        int hy = hp + ky - 3, wx = wp + kx - 3;
        float v = 0.f;
        if (hy >= 0 && hy < H_ && wx >= 0 && wx < W_)
            v = x[((size_t)(n * C_ + c)) * HW_ + hy * W_ + wx];
        s_patch[i] = v;
    }
    __syncthreads();

    for (int i = t; i < DDIM_; i += 256) {
        int c = i / NB_, m = i % NB_;
        float a = 0.f;
        #pragma unroll
        for (int k = 0; k < K2_; k++)
            a += s_patch[c * K2_ + k] * s_atoms[k * NB_ + m];
        s_bout[i] = a;
    }
    __syncthreads();

    {
        int o = t & 63, grp = t >> 6;
        float a = 0.f;
        #pragma unroll
        for (int d = grp * 48; d < grp * 48 + 48; d++)
            a += s_bout[d] * out_w[o * DDIM_ + d];
        s_part[grp][o] = a;
    }
    __syncthreads();
    if (t < OUT_) {
        float r = out_b[t] + s_part[0][t] + s_part[1][t] + s_part[2][t] + s_part[3][t];
        out[((size_t)(n * OUT_ + t)) * HW_ + hp * W_ + wp] = r;
    }
}

extern "C" void kernel_launch(void* const* d_in, const int* in_sizes, int n_in,
                              void* d_out, int out_size, void* d_ws, size_t ws_size,
                              hipStream_t stream) {
    const float* x       = (const float*)d_in[0];
    const float* conv1_w = (const float*)d_in[1];
    const float* conv1_b = (const float*)d_in[2];
    const float* bn1_g   = (const float*)d_in[3];
    const float* bn1_b   = (const float*)d_in[4];
    const float* conv2_w = (const float*)d_in[5];
    const float* conv2_b = (const float*)d_in[6];
    const float* bn2_g   = (const float*)d_in[7];
    const float* bn2_b   = (const float*)d_in[8];
    const float* bases   = (const float*)d_in[9];
    const float* out_w   = (const float*)d_in[10];
    const float* out_b   = (const float*)d_in[11];
    float* out = (float*)d_out;

    float* y1  = (float*)d_ws;                    // N*INTER*HW = 2,097,152
    float* y2  = y1 + (size_t)N_ * INTER_ * HW_;  // N*BC*HW   = 3,538,944
    float* sc1 = y2 + (size_t)N_ * BC_ * HW_;
    float* sh1 = sc1 + INTER_;
    float* sc2 = sh1 + INTER_;
    float* sh2 = sc2 + BC_;

    int tot1 = N_ * INTER_ * HW_;
    int tot2 = N_ * BC_ * HW_;

    k_conv_tiled<C_, INTER_><<<N_ * (H_ / 4) * ((INTER_ + 15) / 16), 256, 0, stream>>>(
        x, conv1_w, conv1_b, y1);
    k_bnstats<<<INTER_, 256, 0, stream>>>(y1, bn1_g, bn1_b, sc1, sh1, INTER_);
    k_bnact<<<(tot1 + 255) / 256, 256, 0, stream>>>(y1, sc1, sh1, INTER_);

    k_conv_tiled<INTER_, BC_><<<N_ * (H_ / 4) * ((BC_ + 15) / 16), 256, 0, stream>>>(
        y1, conv2_w, conv2_b, y2);
    k_bnstats<<<BC_, 256, 0, stream>>>(y2, bn2_g, bn2_b, sc2, sh2, BC_);
    k_bnact<<<(tot2 + 255) / 256, 256, 0, stream>>>(y2, sc2, sh2, BC_);

    k_final<<<NHW_, 256, 0, stream>>>(x, y2, bases, out_w, out_b, out);
}

// Round 3
// 425.554 us; speedup vs baseline: 2.6635x; 1.3484x over previous
//
#include <hip/hip_runtime.h>
#include <hip/hip_bf16.h>

#define N_ 8
#define C_ 32
#define H_ 64
#define W_ 64
#define HW_ (H_*W_)
#define NHW_ (N_*HW_)
#define INTER_ 64
#define BC_ 108
#define KS_ 7
#define K2_ (KS_*KS_)
#define NB_ 6
#define TB_ 18
#define OUT_ 64
#define DDIM_ (C_*NB_)   // 192
#define PCH_ (TB_*C_)    // 576

__inline__ __device__ float wave_reduce_sum(float v) {
    #pragma unroll
    for (int off = 32; off > 0; off >>= 1) v += __shfl_down(v, off);
    return v;
}

// Tiled direct 3x3 conv, pad=1.  Block tile: 16 co x 4 rows x 64 cols.
template<int CIN, int COUT>
__global__ __launch_bounds__(256) void k_conv_tiled(const float* __restrict__ x,
                                                    const float* __restrict__ w,
                                                    const float* __restrict__ b,
                                                    float* __restrict__ y) {
    constexpr int CO_T = 16, ROWS = 4, CI_CH = 8;
    constexpr int CO_TILES = (COUT + CO_T - 1) / CO_T;

    __shared__ float sx[CI_CH][ROWS + 2][68];
    __shared__ float sw[CO_T][CI_CH][12];

    int bid = blockIdx.x;
    int cot = bid % CO_TILES;
    int ht  = (bid / CO_TILES) % (H_ / ROWS);
    int n   = bid / (CO_TILES * (H_ / ROWS));
    int h0  = ht * ROWS;
    int co0 = cot * CO_T;

    int t   = threadIdx.x;
    int w8  = (t & 7) * 8;
    int row = (t >> 3) & 3;
    int cog = t >> 5;

    float acc[2][8];
    #pragma unroll
    for (int o = 0; o < 2; o++)
        #pragma unroll
        for (int j = 0; j < 8; j++) acc[o][j] = 0.f;

    for (int cc = 0; cc < CIN; cc += CI_CH) {
        for (int i = t; i < CI_CH * 6 * 66; i += 256) {
            int col = i % 66;
            int rr  = (i / 66) % 6;
            int ci  = i / 396;
            int hy  = h0 + rr - 1;
            int wx  = col - 1;
            float v = 0.f;
            if (hy >= 0 && hy < H_ && wx >= 0 && wx < W_)
                v = x[(((size_t)n * CIN + cc + ci) * HW_) + hy * W_ + wx];
            sx[ci][rr][col] = v;
        }
        for (int i = t; i < CO_T * CI_CH * 9; i += 256) {
            int k  = i % 9;
            int ci = (i / 9) % CI_CH;
            int co = i / (9 * CI_CH);
            float v = 0.f;
            if (co0 + co < COUT)
                v = w[(((size_t)(co0 + co) * CIN) + cc + ci) * 9 + k];
            sw[co][ci][k] = v;
        }
        __syncthreads();

        #pragma unroll
        for (int ci = 0; ci < CI_CH; ci++) {
            float xr[3][10];
            #pragma unroll
            for (int r = 0; r < 3; r++) {
                const float* base = &sx[ci][row + r][w8];
                float4 a = *(const float4*)base;
                float4 bq = *(const float4*)(base + 4);
                float2 cq = *(const float2*)(base + 8);
                xr[r][0] = a.x;  xr[r][1] = a.y;  xr[r][2] = a.z;  xr[r][3] = a.w;
                xr[r][4] = bq.x; xr[r][5] = bq.y; xr[r][6] = bq.z; xr[r][7] = bq.w;
                xr[r][8] = cq.x; xr[r][9] = cq.y;
            }
            #pragma unroll
            for (int o = 0; o < 2; o++) {
                const float* wb = &sw[cog * 2 + o][ci][0];
                float4 w0 = *(const float4*)wb;
                float4 w1 = *(const float4*)(wb + 4);
                float  w8v = wb[8];
                float wreg[9] = {w0.x, w0.y, w0.z, w0.w, w1.x, w1.y, w1.z, w1.w, w8v};
                #pragma unroll
                for (int r = 0; r < 3; r++)
                    #pragma unroll
                    for (int k = 0; k < 3; k++) {
                        float wv = wreg[r * 3 + k];
                        #pragma unroll
                        for (int j = 0; j < 8; j++)
                            acc[o][j] += xr[r][j + k] * wv;
                    }
            }
        }
        __syncthreads();
    }

    #pragma unroll
    for (int o = 0; o < 2; o++) {
        int co = co0 + cog * 2 + o;
        if (co < COUT) {
            float bb = b[co];
            float* yp = &y[(((size_t)n * COUT + co) * HW_) + (h0 + row) * W_ + w8];
            float4 v0 = make_float4(acc[o][0] + bb, acc[o][1] + bb, acc[o][2] + bb, acc[o][3] + bb);
            float4 v1 = make_float4(acc[o][4] + bb, acc[o][5] + bb, acc[o][6] + bb, acc[o][7] + bb);
            *(float4*)yp = v0;
            *(float4*)(yp + 4) = v1;
        }
    }
}

__global__ void k_bnstats(const float* __restrict__ y, const float* __restrict__ g,
                          const float* __restrict__ bb, float* __restrict__ scale,
                          float* __restrict__ shift, int Cout) {
    int c = blockIdx.x;
    float s = 0.f, s2 = 0.f;
    for (int i = threadIdx.x; i < NHW_; i += blockDim.x) {
        int n = i >> 12;
        int p = i & 4095;
        float v = y[((size_t)(n * Cout + c)) * HW_ + p];
        s += v; s2 += v * v;
    }
    s = wave_reduce_sum(s);
    s2 = wave_reduce_sum(s2);
    __shared__ float sm[16];
    int wid = threadIdx.x >> 6, lane = threadIdx.x & 63;
    if (lane == 0) { sm[wid] = s; sm[8 + wid] = s2; }
    __syncthreads();
    if (threadIdx.x == 0) {
        float ts = 0.f, ts2 = 0.f;
        for (int i = 0; i < (int)(blockDim.x >> 6); i++) { ts += sm[i]; ts2 += sm[8 + i]; }
        float mu  = ts / (float)NHW_;
        float var = ts2 / (float)NHW_ - mu * mu;
        float sc  = g[c] * rsqrtf(var + 1e-5f);
        scale[c] = sc;
        shift[c] = bb[c] - mu * sc;
    }
}

__global__ void k_bnact(float* __restrict__ y, const float* __restrict__ scale,
                        const float* __restrict__ shift, int Cout) {
    int idx = blockIdx.x * blockDim.x + threadIdx.x;
    int total = N_ * Cout * HW_;
    if (idx >= total) return;
    int c = (idx >> 12) % Cout;
    y[idx] = tanhf(y[idx] * scale[c] + shift[c]);
}

// P[n][t*32+c][h][w] = sum_{ky,kx} bases[t][ky*7+kx] * x[n][c][h+ky-3][w+kx-3]
// grid: 512 = n(8) x c(32) x rowhalf(2); block 256 = 4 waves x 64 lanes(cols)
__global__ __launch_bounds__(256) void k_pconv(const float* __restrict__ x,
                                               const float* __restrict__ bases,
                                               float* __restrict__ P) {
    __shared__ float sx[70][40];   // [phys col (wx+3)][phys row]
    int bid = blockIdx.x;
    int rh = bid & 1;
    int c  = (bid >> 1) & 31;
    int n  = bid >> 6;
    int t = threadIdx.x;
    int lane = t & 63, wv = t >> 6;

    const float* xc = x + (((size_t)n * C_ + c) << 12);
    #pragma unroll
    for (int j = 0; j < 10; j++) {
        int p = wv + 4 * j;                 // 0..39
        int grow = rh * 32 - 4 + p;
        {
            int wx = lane - 3;              // -3..60
            float v = 0.f;
            if (grow >= 0 && grow < H_ && wx >= 0) v = xc[(grow << 6) + wx];
            sx[lane][p] = v;
        }
        if (lane < 6) {
            int pc = 64 + lane;
            int wx = pc - 3;                // 61..66
            float v = 0.f;
            if (grow >= 0 && grow < H_ && wx < W_) v = xc[(grow << 6) + wx];
            sx[pc][p] = v;
        }
    }
    __syncthreads();

    int r0 = rh * 32 + wv * 8;              // first output row of this wave
    for (int tp = 0; tp < 9; tp++) {
        float a0[8], a1[8];
        #pragma unroll
        for (int rr = 0; rr < 8; rr++) { a0[rr] = 0.f; a1[rr] = 0.f; }
        #pragma unroll
        for (int kx = 0; kx < 7; kx++) {
            float rw[16];
            const float* sp = &sx[lane + kx][wv * 8];
            #pragma unroll
            for (int q = 0; q < 4; q++) {
                float4 r4 = *(const float4*)(sp + q * 4);
                rw[q * 4 + 0] = r4.x; rw[q * 4 + 1] = r4.y;
                rw[q * 4 + 2] = r4.z; rw[q * 4 + 3] = r4.w;
            }
            #pragma unroll
            for (int ky = 0; ky < 7; ky++) {
                float w0 = bases[(2 * tp) * K2_ + ky * 7 + kx];
                float w1 = bases[(2 * tp + 1) * K2_ + ky * 7 + kx];
                #pragma unroll
                for (int rr = 0; rr < 8; rr++) {
                    float xv = rw[rr + ky + 1];
                    a0[rr] += xv * w0;
                    a1[rr] += xv * w1;
                }
            }
        }
        #pragma unroll
        for (int rr = 0; rr < 8; rr++) {
            int gr = r0 + rr;
            P[(((size_t)n * PCH_ + (2 * tp) * C_ + c) << 12) + (gr << 6) + lane] = a0[rr];
            P[(((size_t)n * PCH_ + (2 * tp + 1) * C_ + c) << 12) + (gr << 6) + lane] = a1[rr];
        }
    }
}

// Y[n][c*6+m][px] = sum_t tanh(bn(y2[m*18+t]))[px] * P[t*32+c][px]
// grid 256 = n(8) x pxblk(32); block 256: t<128 -> c 0..15, else c 16..31
__global__ __launch_bounds__(256) void k_y(const float* __restrict__ y2,
                                           const float* __restrict__ sc2,
                                           const float* __restrict__ sh2,
                                           const float* __restrict__ P,
                                           float* __restrict__ Y) {
    int bid = blockIdx.x;
    int n = bid >> 5;
    int px0 = (bid & 31) << 7;
    int t = threadIdx.x;
    int px = px0 + (t & 127);
    int c0 = (t >> 7) * 16;

    float cf[BC_];
    const float* yb = y2 + (((size_t)n * BC_) << 12) + px;
    #pragma unroll
    for (int ch = 0; ch < BC_; ch++) {
        float raw = yb[(size_t)ch << 12];
        cf[ch] = tanhf(raw * sc2[ch] + sh2[ch]);
    }
    const float* Pb = P + (((size_t)n * PCH_) << 12) + px;
    float* Yb = Y + (((size_t)n * DDIM_) << 12) + px;
    for (int c = c0; c < c0 + 16; c++) {
        float pv[TB_];
        #pragma unroll
        for (int tt = 0; tt < TB_; tt++)
            pv[tt] = Pb[(size_t)(tt * C_ + c) << 12];
        #pragma unroll
        for (int m = 0; m < NB_; m++) {
            float a = 0.f;
            #pragma unroll
            for (int tt = 0; tt < TB_; tt++)
                a += cf[m * TB_ + tt] * pv[tt];
            Yb[(size_t)(c * NB_ + m) << 12] = a;
        }
    }
}

// out[n][o][px] = out_b[o] + sum_d out_w[o][d] * Y[d][px]
// grid 256 = n(8) x pxblk(32, 128 px each); block 256 = (og 0..7)x(pxg 0..31)
__global__ __launch_bounds__(256) void k_proj(const float* __restrict__ Y,
                                              const float* __restrict__ out_w,
                                              const float* __restrict__ out_b,
                                              float* __restrict__ out) {
    __shared__ float swt[DDIM_][OUT_];
    int bid = blockIdx.x;
    int n = bid >> 5;
    int px0 = (bid & 31) << 7;
    int t = threadIdx.x;
    for (int i = t; i < DDIM_ * OUT_; i += 256) {
        int d = i >> 6, o = i & 63;
        swt[d][o] = out_w[o * DDIM_ + d];
    }
    __syncthreads();

    int pxg = t & 31, og = t >> 5;
    int px = px0 + pxg * 4;
    int o0 = og * 8;
    float acc[8][4];
    #pragma unroll
    for (int j = 0; j < 8; j++)
        #pragma unroll
        for (int i = 0; i < 4; i++) acc[j][i] = 0.f;

    const float* Yb = Y + (((size_t)n * DDIM_) << 12) + px;
    for (int d = 0; d < DDIM_; d++) {
        float4 yv = *(const float4*)(Yb + ((size_t)d << 12));
        #pragma unroll
        for (int j = 0; j < 8; j++) {
            float wvv = swt[d][o0 + j];
            acc[j][0] += wvv * yv.x; acc[j][1] += wvv * yv.y;
            acc[j][2] += wvv * yv.z; acc[j][3] += wvv * yv.w;
        }
    }
    #pragma unroll
    for (int j = 0; j < 8; j++) {
        int o = o0 + j;
        float bb = out_b[o];
        float4 v = make_float4(acc[j][0] + bb, acc[j][1] + bb, acc[j][2] + bb, acc[j][3] + bb);
        *(float4*)(out + (((size_t)n * OUT_ + o) << 12) + px) = v;
    }
}

extern "C" void kernel_launch(void* const* d_in, const int* in_sizes, int n_in,
                              void* d_out, int out_size, void* d_ws, size_t ws_size,
                              hipStream_t stream) {
    const float* x       = (const float*)d_in[0];
    const float* conv1_w = (const float*)d_in[1];
    const float* conv1_b = (const float*)d_in[2];
    const float* bn1_g   = (const float*)d_in[3];
    const float* bn1_b   = (const float*)d_in[4];
    const float* conv2_w = (const float*)d_in[5];
    const float* conv2_b = (const float*)d_in[6];
    const float* bn2_g   = (const float*)d_in[7];
    const float* bn2_b   = (const float*)d_in[8];
    const float* bases   = (const float*)d_in[9];
    const float* out_w   = (const float*)d_in[10];
    const float* out_b   = (const float*)d_in[11];
    float* out = (float*)d_out;

    float* y1  = (float*)d_ws;                    // 2,097,152
    float* y2  = y1 + (size_t)N_ * INTER_ * HW_;  // 3,538,944
    float* P   = y2 + (size_t)N_ * BC_ * HW_;     // 18,874,368
    float* Yt  = P  + (size_t)N_ * PCH_ * HW_;    // 6,291,456
    float* sc1 = Yt + (size_t)N_ * DDIM_ * HW_;
    float* sh1 = sc1 + INTER_;
    float* sc2 = sh1 + INTER_;
    float* sh2 = sc2 + BC_;

    int tot1 = N_ * INTER_ * HW_;

    k_conv_tiled<C_, INTER_><<<N_ * (H_ / 4) * (INTER_ / 16), 256, 0, stream>>>(
        x, conv1_w, conv1_b, y1);
    k_bnstats<<<INTER_, 256, 0, stream>>>(y1, bn1_g, bn1_b, sc1, sh1, INTER_);
    k_bnact<<<(tot1 + 255) / 256, 256, 0, stream>>>(y1, sc1, sh1, INTER_);

    k_conv_tiled<INTER_, BC_><<<N_ * (H_ / 4) * ((BC_ + 15) / 16), 256, 0, stream>>>(
        y1, conv2_w, conv2_b, y2);
    k_bnstats<<<BC_, 256, 0, stream>>>(y2, bn2_g, bn2_b, sc2, sh2, BC_);

    k_pconv<<<N_ * C_ * 2, 256, 0, stream>>>(x, bases, P);
    k_y<<<N_ * 32, 256, 0, stream>>>(y2, sc2, sh2, P, Yt);
    k_proj<<<N_ * 32, 256, 0, stream>>>(Yt, out_w, out_b, out);
}

// Round 4
// 331.747 us; speedup vs baseline: 3.4166x; 1.2828x over previous
//
#include <hip/hip_runtime.h>
#include <hip/hip_bf16.h>

#define N_ 8
#define C_ 32
#define H_ 64
#define W_ 64
#define HW_ (H_*W_)
#define NHW_ (N_*HW_)
#define INTER_ 64
#define BC_ 108
#define KS_ 7
#define K2_ (KS_*KS_)
#define NB_ 6
#define TB_ 18
#define OUT_ 64
#define DDIM_ (C_*NB_)   // 192
#define PCH_ (TB_*C_)    // 576

typedef __attribute__((ext_vector_type(8))) short short8;
typedef __attribute__((ext_vector_type(4))) float f32x4;

__device__ __forceinline__ unsigned short f2bf(float f) {
    union { float f; unsigned u; } v; v.f = f;
    unsigned r = v.u + 0x7fffu + ((v.u >> 16) & 1u);
    return (unsigned short)(r >> 16);
}

__inline__ __device__ float wave_reduce_sum(float v) {
    #pragma unroll
    for (int off = 32; off > 0; off >>= 1) v += __shfl_down(v, off);
    return v;
}

// ---------------------------------------------------------------------------
// prep: cast x NCHW f32 -> xb NHWC bf16 ; transpose weights to [s][co][ci] bf16
// blocks 0..511: x tiles; 512..583: conv1_w; 584..835: conv2_w (co padded 112)
__global__ __launch_bounds__(256) void k_prep(const float* __restrict__ x,
                                              const float* __restrict__ w1,
                                              const float* __restrict__ w2,
                                              unsigned short* __restrict__ xb,
                                              unsigned short* __restrict__ wb1,
                                              unsigned short* __restrict__ wb2) {
    __shared__ unsigned short sT[64 * 36];
    int bid = blockIdx.x, t = threadIdx.x;
    if (bid < 512) {
        int n = bid >> 6, hw0 = (bid << 6) & 4095;
        for (int i = t; i < 2048; i += 256) {
            int c = i >> 6, px = i & 63;
            float v = x[(((size_t)n * C_ + c) << 12) + hw0 + px];
            sT[px * 36 + c] = f2bf(v);
        }
        __syncthreads();
        unsigned int* xd = (unsigned int*)xb;
        for (int i = t; i < 1024; i += 256) {
            int px = i >> 4, cw = i & 15;
            unsigned int lo = sT[px * 36 + cw * 2], hi = sT[px * 36 + cw * 2 + 1];
            xd[(((size_t)n << 12) + hw0 + px) * 16 + cw] = lo | (hi << 16);
        }
    } else if (bid < 584) {
        int i = (bid - 512) * 256 + t;       // < 18432 = 9*64*32
        int ci = i & 31, co = (i >> 5) & 63, s = i >> 11;
        wb1[i] = f2bf(w1[((co << 5) + ci) * 9 + s]);
    } else {
        int i = (bid - 584) * 256 + t;       // < 64512 = 9*112*64
        int ci = i & 63, co = (i >> 6) % 112, s = i / (112 * 64);
        unsigned short v = 0;
        if (co < BC_) v = f2bf(w2[((co << 6) + ci) * 9 + s]);
        wb2[i] = v;
    }
}

// ---------------------------------------------------------------------------
// MFMA conv3x3 (pad=1): D[co][pix] += sum_s W_s[co][ci] * X[ci][pix shifted]
// block: 2 output rows x 64 cols = 128 px (8 n-tiles), full COUT (COT m-tiles)
// wave: 2 n-tiles x COT m-tiles. grid = N*(H/2) = 256.
template<int CIN, int COT>
__global__ __launch_bounds__(256) void k_conv_mfma(const unsigned short* __restrict__ xb, // NHWC bf16
                                                   const unsigned short* __restrict__ wb, // [9][COT*16][CIN]
                                                   const float* __restrict__ bias,
                                                   float* __restrict__ y,                 // NCHW f32
                                                   int COUT_real) {
    constexpr int CPAD = CIN + 8;            // bf16 stride per (row,col) slice
    constexpr int KSTEPS = CIN / 32;
    __shared__ unsigned short sx[4 * 66 * CPAD];
    __shared__ unsigned short sw[COT * 16 * CPAD];

    int bid = blockIdx.x;
    int rp = bid & 31, n = bid >> 5;
    int h0 = rp * 2;
    int t = threadIdx.x;
    int lane = t & 63, wv = t >> 6;
    int q = lane >> 4, n15 = lane & 15;

    // stage X tile: rows h0-1..h0+2, cols -1..64 (phys 0..65), CIN bf16 each
    {
        const unsigned int* xg = (const unsigned int*)xb + (size_t)n * HW_ * (CIN / 2);
        unsigned int* sxd = (unsigned int*)sx;
        constexpr int DW = CIN / 2;
        constexpr int DWPT = DW / 8;         // 8 threads per slice
        int part = t & 7;
        for (int sl = (t >> 3); sl < 264; sl += 32) {
            int r = sl / 66, col = sl % 66;
            int hh = h0 - 1 + r, ww = col - 1;
            unsigned int v[DWPT];
            #pragma unroll
            for (int i = 0; i < DWPT; i++) v[i] = 0;
            if (hh >= 0 && hh < H_ && ww >= 0 && ww < W_) {
                const unsigned int* g = xg + (size_t)(hh * W_ + ww) * DW + part * DWPT;
                #pragma unroll
                for (int i = 0; i < DWPT; i++) v[i] = g[i];
            }
            unsigned int* d = sxd + sl * (CPAD / 2) + part * DWPT;
            #pragma unroll
            for (int i = 0; i < DWPT; i++) d[i] = v[i];
        }
    }

    f32x4 acc[2][COT];
    #pragma unroll
    for (int a = 0; a < 2; a++)
        #pragma unroll
        for (int m = 0; m < COT; m++) acc[a][m] = (f32x4){0.f, 0.f, 0.f, 0.f};

    for (int s = 0; s < 9; s++) {
        __syncthreads();
        // stage weights for shift s (padded co rows already zeroed in prep)
        {
            const unsigned int* wg = (const unsigned int*)wb + (size_t)s * COT * 16 * (CIN / 2);
            unsigned int* swd = (unsigned int*)sw;
            #pragma unroll 2
            for (int e = t; e < COT * 16 * CIN / 2; e += 256) {
                int co = e / (CIN / 2), cw = e % (CIN / 2);
                swd[co * (CPAD / 2) + cw] = wg[e];
            }
        }
        __syncthreads();
        int dy = s / 3, dx = s % 3;
        #pragma unroll
        for (int kc = 0; kc < KSTEPS; kc++) {
            int ci0 = kc * 32;
            short8 bfr[2];
            #pragma unroll
            for (int ntl = 0; ntl < 2; ntl++) {
                int nt = wv * 2 + ntl;
                int r_out = nt >> 2, col0 = (nt & 3) * 16;
                bfr[ntl] = *(const short8*)(sx + ((r_out + dy) * 66 + col0 + n15 + dx) * CPAD + ci0 + q * 8);
            }
            #pragma unroll
            for (int mt = 0; mt < COT; mt++) {
                short8 afr = *(const short8*)(sw + (mt * 16 + n15) * CPAD + ci0 + q * 8);
                acc[0][mt] = __builtin_amdgcn_mfma_f32_16x16x32_bf16(afr, bfr[0], acc[0][mt], 0, 0, 0);
                acc[1][mt] = __builtin_amdgcn_mfma_f32_16x16x32_bf16(afr, bfr[1], acc[1][mt], 0, 0, 0);
            }
        }
    }

    // epilogue: D row = co = mt*16 + q*4 + reg ; D col = pix = nt*16 + n15
    #pragma unroll
    for (int ntl = 0; ntl < 2; ntl++) {
        int nt = wv * 2 + ntl;
        int h = h0 + (nt >> 2), wcol = (nt & 3) * 16 + n15;
        #pragma unroll
        for (int mt = 0; mt < COT; mt++) {
            #pragma unroll
            for (int reg = 0; reg < 4; reg++) {
                int co = mt * 16 + q * 4 + reg;
                if (co < COUT_real)
                    y[(((size_t)n * COUT_real + co) << 12) + h * W_ + wcol] = acc[ntl][mt][reg] + bias[co];
            }
        }
    }
}

// ---------------------------------------------------------------------------
__global__ void k_bnstats(const float* __restrict__ y, const float* __restrict__ g,
                          const float* __restrict__ bb, float* __restrict__ scale,
                          float* __restrict__ shift, int Cout) {
    int c = blockIdx.x;
    float s = 0.f, s2 = 0.f;
    for (int i = threadIdx.x; i < NHW_; i += blockDim.x) {
        int n = i >> 12;
        int p = i & 4095;
        float v = y[((size_t)(n * Cout + c)) * HW_ + p];
        s += v; s2 += v * v;
    }
    s = wave_reduce_sum(s);
    s2 = wave_reduce_sum(s2);
    __shared__ float sm[16];
    int wid = threadIdx.x >> 6, lane = threadIdx.x & 63;
    if (lane == 0) { sm[wid] = s; sm[8 + wid] = s2; }
    __syncthreads();
    if (threadIdx.x == 0) {
        float ts = 0.f, ts2 = 0.f;
        for (int i = 0; i < (int)(blockDim.x >> 6); i++) { ts += sm[i]; ts2 += sm[8 + i]; }
        float mu  = ts / (float)NHW_;
        float var = ts2 / (float)NHW_ - mu * mu;
        float sc  = g[c] * rsqrtf(var + 1e-5f);
        scale[c] = sc;
        shift[c] = bb[c] - mu * sc;
    }
}

// y1 NCHW f32 -> tanh(bn) -> y1b NHWC bf16 (LDS transpose)
__global__ __launch_bounds__(256) void k_bntr(const float* __restrict__ y1,
                                              const float* __restrict__ sc,
                                              const float* __restrict__ sh,
                                              unsigned short* __restrict__ y1b) {
    __shared__ unsigned short sT[64 * 68];
    int bid = blockIdx.x, t = threadIdx.x;
    int n = bid >> 6, hw0 = (bid << 6) & 4095;
    for (int i = t; i < 4096; i += 256) {
        int c = i >> 6, px = i & 63;
        float v = y1[(((size_t)n * INTER_ + c) << 12) + hw0 + px];
        sT[px * 68 + c] = f2bf(tanhf(v * sc[c] + sh[c]));
    }
    __syncthreads();
    unsigned int* yd = (unsigned int*)y1b;
    for (int i = t; i < 2048; i += 256) {
        int px = i >> 5, cw = i & 31;
        unsigned int lo = sT[px * 68 + cw * 2], hi = sT[px * 68 + cw * 2 + 1];
        yd[(((size_t)n << 12) + hw0 + px) * 32 + cw] = lo | (hi << 16);
    }
}

// ---------------------------------------------------------------------------
// P[n][t*32+c][h][w] = bases[t] (x) 7x7-correlate x[n][c]
__global__ __launch_bounds__(256) void k_pconv(const float* __restrict__ x,
                                               const float* __restrict__ bases,
                                               float* __restrict__ P) {
    __shared__ float sx[70][44];   // stride 44: conflict-free b128 phases
    int bid = blockIdx.x;
    int rh = bid & 1;
    int c  = (bid >> 1) & 31;
    int n  = bid >> 6;
    int t = threadIdx.x;
    int lane = t & 63, wv = t >> 6;

    const float* xc = x + (((size_t)n * C_ + c) << 12);
    #pragma unroll
    for (int j = 0; j < 10; j++) {
        int p = wv + 4 * j;
        int grow = rh * 32 - 4 + p;
        {
            int wx = lane - 3;
            float v = 0.f;
            if (grow >= 0 && grow < H_ && wx >= 0) v = xc[(grow << 6) + wx];
            sx[lane][p] = v;
        }
        if (lane < 6) {
            int pc = 64 + lane;
            int wx = pc - 3;
            float v = 0.f;
            if (grow >= 0 && grow < H_ && wx < W_) v = xc[(grow << 6) + wx];
            sx[pc][p] = v;
        }
    }
    __syncthreads();

    int r0 = rh * 32 + wv * 8;
    for (int tp = 0; tp < 9; tp++) {
        float a0[8], a1[8];
        #pragma unroll
        for (int rr = 0; rr < 8; rr++) { a0[rr] = 0.f; a1[rr] = 0.f; }
        #pragma unroll
        for (int kx = 0; kx < 7; kx++) {
            float rw[16];
            const float* sp = &sx[lane + kx][wv * 8];
            #pragma unroll
            for (int qq = 0; qq < 4; qq++) {
                float4 r4 = *(const float4*)(sp + qq * 4);
                rw[qq * 4 + 0] = r4.x; rw[qq * 4 + 1] = r4.y;
                rw[qq * 4 + 2] = r4.z; rw[qq * 4 + 3] = r4.w;
            }
            #pragma unroll
            for (int ky = 0; ky < 7; ky++) {
                float w0 = bases[(2 * tp) * K2_ + ky * 7 + kx];
                float w1 = bases[(2 * tp + 1) * K2_ + ky * 7 + kx];
                #pragma unroll
                for (int rr = 0; rr < 8; rr++) {
                    float xv = rw[rr + ky + 1];
                    a0[rr] += xv * w0;
                    a1[rr] += xv * w1;
                }
            }
        }
        #pragma unroll
        for (int rr = 0; rr < 8; rr++) {
            int gr = r0 + rr;
            P[(((size_t)n * PCH_ + (2 * tp) * C_ + c) << 12) + (gr << 6) + lane] = a0[rr];
            P[(((size_t)n * PCH_ + (2 * tp + 1) * C_ + c) << 12) + (gr << 6) + lane] = a1[rr];
        }
    }
}

// Y[n][c*6+m][px] = sum_t tanh(bn(y2[m*18+t]))[px] * P[t*32+c][px]
__global__ __launch_bounds__(256) void k_y(const float* __restrict__ y2,
                                           const float* __restrict__ sc2,
                                           const float* __restrict__ sh2,
                                           const float* __restrict__ P,
                                           float* __restrict__ Y) {
    int bid = blockIdx.x;
    int n = bid >> 5;
    int px0 = (bid & 31) << 7;
    int t = threadIdx.x;
    int px = px0 + (t & 127);
    int c0 = (t >> 7) * 16;

    float cf[BC_];
    const float* yb = y2 + (((size_t)n * BC_) << 12) + px;
    #pragma unroll
    for (int ch = 0; ch < BC_; ch++) {
        float raw = yb[(size_t)ch << 12];
        cf[ch] = tanhf(raw * sc2[ch] + sh2[ch]);
    }
    const float* Pb = P + (((size_t)n * PCH_) << 12) + px;
    float* Yb = Y + (((size_t)n * DDIM_) << 12) + px;
    for (int c = c0; c < c0 + 16; c++) {
        float pv[TB_];
        #pragma unroll
        for (int tt = 0; tt < TB_; tt++)
            pv[tt] = Pb[(size_t)(tt * C_ + c) << 12];
        #pragma unroll
        for (int m = 0; m < NB_; m++) {
            float a = 0.f;
            #pragma unroll
            for (int tt = 0; tt < TB_; tt++)
                a += cf[m * TB_ + tt] * pv[tt];
            Yb[(size_t)(c * NB_ + m) << 12] = a;
        }
    }
}

// out[n][o][px] = out_b[o] + sum_d out_w[o][d] * Y[d][px]
__global__ __launch_bounds__(256) void k_proj(const float* __restrict__ Y,
                                              const float* __restrict__ out_w,
                                              const float* __restrict__ out_b,
                                              float* __restrict__ out) {
    __shared__ float swt[DDIM_][OUT_];
    int bid = blockIdx.x;
    int n = bid >> 5;
    int px0 = (bid & 31) << 7;
    int t = threadIdx.x;
    for (int i = t; i < DDIM_ * OUT_; i += 256) {
        int d = i >> 6, o = i & 63;
        swt[d][o] = out_w[o * DDIM_ + d];
    }
    __syncthreads();

    int pxg = t & 31, og = t >> 5;
    int px = px0 + pxg * 4;
    int o0 = og * 8;
    float acc[8][4];
    #pragma unroll
    for (int j = 0; j < 8; j++)
        #pragma unroll
        for (int i = 0; i < 4; i++) acc[j][i] = 0.f;

    const float* Yb = Y + (((size_t)n * DDIM_) << 12) + px;
    for (int d = 0; d < DDIM_; d++) {
        float4 yv = *(const float4*)(Yb + ((size_t)d << 12));
        #pragma unroll
        for (int j = 0; j < 8; j++) {
            float wvv = swt[d][o0 + j];
            acc[j][0] += wvv * yv.x; acc[j][1] += wvv * yv.y;
            acc[j][2] += wvv * yv.z; acc[j][3] += wvv * yv.w;
        }
    }
    #pragma unroll
    for (int j = 0; j < 8; j++) {
        int o = o0 + j;
        float bb = out_b[o];
        float4 v = make_float4(acc[j][0] + bb, acc[j][1] + bb, acc[j][2] + bb, acc[j][3] + bb);
        *(float4*)(out + (((size_t)n * OUT_ + o) << 12) + px) = v;
    }
}

extern "C" void kernel_launch(void* const* d_in, const int* in_sizes, int n_in,
                              void* d_out, int out_size, void* d_ws, size_t ws_size,
                              hipStream_t stream) {
    const float* x       = (const float*)d_in[0];
    const float* conv1_w = (const float*)d_in[1];
    const float* conv1_b = (const float*)d_in[2];
    const float* bn1_g   = (const float*)d_in[3];
    const float* bn1_b   = (const float*)d_in[4];
    const float* conv2_w = (const float*)d_in[5];
    const float* conv2_b = (const float*)d_in[6];
    const float* bn2_g   = (const float*)d_in[7];
    const float* bn2_b   = (const float*)d_in[8];
    const float* bases   = (const float*)d_in[9];
    const float* out_w   = (const float*)d_in[10];
    const float* out_b   = (const float*)d_in[11];
    float* out = (float*)d_out;

    float* y1  = (float*)d_ws;                    // 2,097,152 f32
    float* y2  = y1 + (size_t)N_ * INTER_ * HW_;  // 3,538,944 f32
    float* P   = y2 + (size_t)N_ * BC_ * HW_;     // 18,874,368 f32
    float* Yt  = P  + (size_t)N_ * PCH_ * HW_;    // 6,291,456 f32
    float* sc1 = Yt + (size_t)N_ * DDIM_ * HW_;
    float* sh1 = sc1 + INTER_;
    float* sc2 = sh1 + INTER_;
    float* sh2 = sc2 + BC_;

    // bf16 scratch aliases regions that are only written later:
    // xb & y1b live inside P (P written at k_pconv, after conv2 consumed them)
    unsigned short* xb  = (unsigned short*)P;                 // 1,048,576 bf16
    unsigned short* y1b = xb + (size_t)NHW_ * C_;             // 2,097,152 bf16
    // weight buffers live inside Yt (written at k_y, after conv2)
    unsigned short* wb1 = (unsigned short*)Yt;                // 18,432 bf16
    unsigned short* wb2 = wb1 + 9 * 64 * 32;                  // 64,512 bf16

    k_prep<<<836, 256, 0, stream>>>(x, conv1_w, conv2_w, xb, wb1, wb2);

    k_conv_mfma<C_, 4><<<N_ * (H_ / 2), 256, 0, stream>>>(xb, wb1, conv1_b, y1, INTER_);
    k_bnstats<<<INTER_, 256, 0, stream>>>(y1, bn1_g, bn1_b, sc1, sh1, INTER_);
    k_bntr<<<512, 256, 0, stream>>>(y1, sc1, sh1, y1b);

    k_conv_mfma<INTER_, 7><<<N_ * (H_ / 2), 256, 0, stream>>>(y1b, wb2, conv2_b, y2, BC_);
    k_bnstats<<<BC_, 256, 0, stream>>>(y2, bn2_g, bn2_b, sc2, sh2, BC_);

    k_pconv<<<N_ * C_ * 2, 256, 0, stream>>>(x, bases, P);
    k_y<<<N_ * 32, 256, 0, stream>>>(y2, sc2, sh2, P, Yt);
    k_proj<<<N_ * 32, 256, 0, stream>>>(Yt, out_w, out_b, out);
}

// Round 5
// 248.275 us; speedup vs baseline: 4.5653x; 1.3362x over previous
//
#include <hip/hip_runtime.h>
#include <hip/hip_bf16.h>

#define N_ 8
#define C_ 32
#define H_ 64
#define W_ 64
#define HW_ (H_*W_)
#define NHW_ (N_*HW_)
#define INTER_ 64
#define BC_ 108
#define KS_ 7
#define K2_ (KS_*KS_)
#define NB_ 6
#define TB_ 18
#define OUT_ 64
#define DDIM_ (C_*NB_)   // 192
#define PCH_ (TB_*C_)    // 576

typedef __attribute__((ext_vector_type(8))) short short8;
typedef __attribute__((ext_vector_type(4))) float f32x4;

__device__ __forceinline__ unsigned short f2bf(float f) {
    union { float f; unsigned u; } v; v.f = f;
    unsigned r = v.u + 0x7fffu + ((v.u >> 16) & 1u);
    return (unsigned short)(r >> 16);
}

__inline__ __device__ float wave_reduce_sum(float v) {
    #pragma unroll
    for (int off = 32; off > 0; off >>= 1) v += __shfl_down(v, off);
    return v;
}

// ---------------------------------------------------------------------------
// prep: cast x NCHW f32 -> xb NHWC bf16 ; transpose weights to [s][co][ci] bf16
__global__ __launch_bounds__(256) void k_prep(const float* __restrict__ x,
                                              const float* __restrict__ w1,
                                              const float* __restrict__ w2,
                                              unsigned short* __restrict__ xb,
                                              unsigned short* __restrict__ wb1,
                                              unsigned short* __restrict__ wb2) {
    __shared__ unsigned short sT[64 * 36];
    int bid = blockIdx.x, t = threadIdx.x;
    if (bid < 512) {
        int n = bid >> 6, hw0 = (bid << 6) & 4095;
        for (int i = t; i < 2048; i += 256) {
            int c = i >> 6, px = i & 63;
            float v = x[(((size_t)n * C_ + c) << 12) + hw0 + px];
            sT[px * 36 + c] = f2bf(v);
        }
        __syncthreads();
        unsigned int* xd = (unsigned int*)xb;
        for (int i = t; i < 1024; i += 256) {
            int px = i >> 4, cw = i & 15;
            unsigned int lo = sT[px * 36 + cw * 2], hi = sT[px * 36 + cw * 2 + 1];
            xd[(((size_t)n << 12) + hw0 + px) * 16 + cw] = lo | (hi << 16);
        }
    } else if (bid < 584) {
        int i = (bid - 512) * 256 + t;       // < 18432 = 9*64*32
        int ci = i & 31, co = (i >> 5) & 63, s = i >> 11;
        wb1[i] = f2bf(w1[((co << 5) + ci) * 9 + s]);
    } else {
        int i = (bid - 584) * 256 + t;       // < 64512 = 9*112*64
        int ci = i & 63, co = (i >> 6) % 112, s = i / (112 * 64);
        unsigned short v = 0;
        if (co < BC_) v = f2bf(w2[((co << 6) + ci) * 9 + s]);
        wb2[i] = v;
    }
}

// ---------------------------------------------------------------------------
// MFMA conv3x3 (pad=1)
template<int CIN, int COT>
__global__ __launch_bounds__(256) void k_conv_mfma(const unsigned short* __restrict__ xb,
                                                   const unsigned short* __restrict__ wb,
                                                   const float* __restrict__ bias,
                                                   float* __restrict__ y,
                                                   int COUT_real) {
    constexpr int CPAD = CIN + 8;
    constexpr int KSTEPS = CIN / 32;
    __shared__ unsigned short sx[4 * 66 * CPAD];
    __shared__ unsigned short sw[COT * 16 * CPAD];

    int bid = blockIdx.x;
    int rp = bid & 31, n = bid >> 5;
    int h0 = rp * 2;
    int t = threadIdx.x;
    int lane = t & 63, wv = t >> 6;
    int q = lane >> 4, n15 = lane & 15;

    {
        const unsigned int* xg = (const unsigned int*)xb + (size_t)n * HW_ * (CIN / 2);
        unsigned int* sxd = (unsigned int*)sx;
        constexpr int DW = CIN / 2;
        constexpr int DWPT = DW / 8;
        int part = t & 7;
        for (int sl = (t >> 3); sl < 264; sl += 32) {
            int r = sl / 66, col = sl % 66;
            int hh = h0 - 1 + r, ww = col - 1;
            unsigned int v[DWPT];
            #pragma unroll
            for (int i = 0; i < DWPT; i++) v[i] = 0;
            if (hh >= 0 && hh < H_ && ww >= 0 && ww < W_) {
                const unsigned int* g = xg + (size_t)(hh * W_ + ww) * DW + part * DWPT;
                #pragma unroll
                for (int i = 0; i < DWPT; i++) v[i] = g[i];
            }
            unsigned int* d = sxd + sl * (CPAD / 2) + part * DWPT;
            #pragma unroll
            for (int i = 0; i < DWPT; i++) d[i] = v[i];
        }
    }

    f32x4 acc[2][COT];
    #pragma unroll
    for (int a = 0; a < 2; a++)
        #pragma unroll
        for (int m = 0; m < COT; m++) acc[a][m] = (f32x4){0.f, 0.f, 0.f, 0.f};

    for (int s = 0; s < 9; s++) {
        __syncthreads();
        {
            const unsigned int* wg = (const unsigned int*)wb + (size_t)s * COT * 16 * (CIN / 2);
            unsigned int* swd = (unsigned int*)sw;
            #pragma unroll 2
            for (int e = t; e < COT * 16 * CIN / 2; e += 256) {
                int co = e / (CIN / 2), cw = e % (CIN / 2);
                swd[co * (CPAD / 2) + cw] = wg[e];
            }
        }
        __syncthreads();
        int dy = s / 3, dx = s % 3;
        #pragma unroll
        for (int kc = 0; kc < KSTEPS; kc++) {
            int ci0 = kc * 32;
            short8 bfr[2];
            #pragma unroll
            for (int ntl = 0; ntl < 2; ntl++) {
                int nt = wv * 2 + ntl;
                int r_out = nt >> 2, col0 = (nt & 3) * 16;
                bfr[ntl] = *(const short8*)(sx + ((r_out + dy) * 66 + col0 + n15 + dx) * CPAD + ci0 + q * 8);
            }
            #pragma unroll
            for (int mt = 0; mt < COT; mt++) {
                short8 afr = *(const short8*)(sw + (mt * 16 + n15) * CPAD + ci0 + q * 8);
                acc[0][mt] = __builtin_amdgcn_mfma_f32_16x16x32_bf16(afr, bfr[0], acc[0][mt], 0, 0, 0);
                acc[1][mt] = __builtin_amdgcn_mfma_f32_16x16x32_bf16(afr, bfr[1], acc[1][mt], 0, 0, 0);
            }
        }
    }

    #pragma unroll
    for (int ntl = 0; ntl < 2; ntl++) {
        int nt = wv * 2 + ntl;
        int h = h0 + (nt >> 2), wcol = (nt & 3) * 16 + n15;
        #pragma unroll
        for (int mt = 0; mt < COT; mt++) {
            #pragma unroll
            for (int reg = 0; reg < 4; reg++) {
                int co = mt * 16 + q * 4 + reg;
                if (co < COUT_real)
                    y[(((size_t)n * COUT_real + co) << 12) + h * W_ + wcol] = acc[ntl][mt][reg] + bias[co];
            }
        }
    }
}

// ---------------------------------------------------------------------------
// BN partial sums: grid = Cout*8, block (c,n) sums y[n,c,:] (4096 elems)
__global__ __launch_bounds__(256) void k_bnpart(const float* __restrict__ y,
                                                float2* __restrict__ part, int Cout) {
    int bid = blockIdx.x;
    int c = bid >> 3, n = bid & 7;
    int t = threadIdx.x;
    const float* p = y + (((size_t)n * Cout + c) << 12) + t * 16;
    float s = 0.f, s2 = 0.f;
    #pragma unroll
    for (int j = 0; j < 4; j++) {
        float4 v = *(const float4*)(p + j * 4);
        s += v.x + v.y + v.z + v.w;
        s2 += v.x * v.x + v.y * v.y + v.z * v.z + v.w * v.w;
    }
    s = wave_reduce_sum(s);
    s2 = wave_reduce_sum(s2);
    __shared__ float sm[8];
    int wid = t >> 6, lane = t & 63;
    if (lane == 0) { sm[wid] = s; sm[4 + wid] = s2; }
    __syncthreads();
    if (t == 0) {
        float2 r;
        r.x = sm[0] + sm[1] + sm[2] + sm[3];
        r.y = sm[4] + sm[5] + sm[6] + sm[7];
        part[c * 8 + n] = r;
    }
}

// y1 NCHW f32 -> tanh(bn) -> y1b NHWC bf16 (finalize BN inline)
__global__ __launch_bounds__(256) void k_bntr(const float* __restrict__ y1,
                                              const float2* __restrict__ part,
                                              const float* __restrict__ g,
                                              const float* __restrict__ bb,
                                              unsigned short* __restrict__ y1b) {
    __shared__ unsigned short sT[64 * 68];
    __shared__ float scs[INTER_], shs[INTER_];
    int bid = blockIdx.x, t = threadIdx.x;
    int n = bid >> 6, hw0 = (bid << 6) & 4095;
    if (t < INTER_) {
        float s = 0.f, s2 = 0.f;
        #pragma unroll
        for (int j = 0; j < 8; j++) { float2 p = part[t * 8 + j]; s += p.x; s2 += p.y; }
        float mu = s / (float)NHW_, var = s2 / (float)NHW_ - mu * mu;
        float sc = g[t] * rsqrtf(var + 1e-5f);
        scs[t] = sc; shs[t] = bb[t] - mu * sc;
    }
    __syncthreads();
    for (int i = t; i < 4096; i += 256) {
        int c = i >> 6, px = i & 63;
        float v = y1[(((size_t)n * INTER_ + c) << 12) + hw0 + px];
        sT[px * 68 + c] = f2bf(tanhf(v * scs[c] + shs[c]));
    }
    __syncthreads();
    unsigned int* yd = (unsigned int*)y1b;
    for (int i = t; i < 2048; i += 256) {
        int px = i >> 5, cw = i & 31;
        unsigned int lo = sT[px * 68 + cw * 2], hi = sT[px * 68 + cw * 2 + 1];
        yd[(((size_t)n << 12) + hw0 + px) * 32 + cw] = lo | (hi << 16);
    }
}

// ---------------------------------------------------------------------------
// P[n][t*32+c][h][w] = bases[t] 7x7-correlate x[n][c]
__global__ __launch_bounds__(256) void k_pconv(const float* __restrict__ x,
                                               const float* __restrict__ bases,
                                               float* __restrict__ P) {
    __shared__ float sx[70][44];
    int bid = blockIdx.x;
    int rh = bid & 1;
    int c  = (bid >> 1) & 31;
    int n  = bid >> 6;
    int t = threadIdx.x;
    int lane = t & 63, wv = t >> 6;

    const float* xc = x + (((size_t)n * C_ + c) << 12);
    #pragma unroll
    for (int j = 0; j < 10; j++) {
        int p = wv + 4 * j;
        int grow = rh * 32 - 4 + p;
        {
            int wx = lane - 3;
            float v = 0.f;
            if (grow >= 0 && grow < H_ && wx >= 0) v = xc[(grow << 6) + wx];
            sx[lane][p] = v;
        }
        if (lane < 6) {
            int pc = 64 + lane;
            int wx = pc - 3;
            float v = 0.f;
            if (grow >= 0 && grow < H_ && wx < W_) v = xc[(grow << 6) + wx];
            sx[pc][p] = v;
        }
    }
    __syncthreads();

    int r0 = rh * 32 + wv * 8;
    for (int tp = 0; tp < 9; tp++) {
        float a0[8], a1[8];
        #pragma unroll
        for (int rr = 0; rr < 8; rr++) { a0[rr] = 0.f; a1[rr] = 0.f; }
        #pragma unroll
        for (int kx = 0; kx < 7; kx++) {
            float rw[16];
            const float* sp = &sx[lane + kx][wv * 8];
            #pragma unroll
            for (int qq = 0; qq < 4; qq++) {
                float4 r4 = *(const float4*)(sp + qq * 4);
                rw[qq * 4 + 0] = r4.x; rw[qq * 4 + 1] = r4.y;
                rw[qq * 4 + 2] = r4.z; rw[qq * 4 + 3] = r4.w;
            }
            #pragma unroll
            for (int ky = 0; ky < 7; ky++) {
                float w0 = bases[(2 * tp) * K2_ + ky * 7 + kx];
                float w1 = bases[(2 * tp + 1) * K2_ + ky * 7 + kx];
                #pragma unroll
                for (int rr = 0; rr < 8; rr++) {
                    float xv = rw[rr + ky + 1];
                    a0[rr] += xv * w0;
                    a1[rr] += xv * w1;
                }
            }
        }
        #pragma unroll
        for (int rr = 0; rr < 8; rr++) {
            int gr = r0 + rr;
            P[(((size_t)n * PCH_ + (2 * tp) * C_ + c) << 12) + (gr << 6) + lane] = a0[rr];
            P[(((size_t)n * PCH_ + (2 * tp + 1) * C_ + c) << 12) + (gr << 6) + lane] = a1[rr];
        }
    }
}

// ---------------------------------------------------------------------------
// Y[n][c*6+m][px] = sum_t tanh(bn(y2[m*18+t]))[px] * P[t*32+c][px]
// grid 512 = n(8) x pxblk(64, 64 px each); block 256 = 4 cgrp x 64 px
__global__ __launch_bounds__(256) void k_y(const float* __restrict__ y2,
                                           const float2* __restrict__ part,
                                           const float* __restrict__ g,
                                           const float* __restrict__ bb,
                                           const float* __restrict__ P,
                                           float* __restrict__ Y) {
    __shared__ float scs[BC_], shs[BC_];
    __shared__ float cfs[BC_][64];
    int bid = blockIdx.x;
    int n = bid >> 6, px0 = (bid & 63) << 6;
    int t = threadIdx.x;

    if (t < BC_) {
        float s = 0.f, s2 = 0.f;
        #pragma unroll
        for (int j = 0; j < 8; j++) { float2 p = part[t * 8 + j]; s += p.x; s2 += p.y; }
        float mu = s / (float)NHW_, var = s2 / (float)NHW_ - mu * mu;
        float sc = g[t] * rsqrtf(var + 1e-5f);
        scs[t] = sc; shs[t] = bb[t] - mu * sc;
    }
    __syncthreads();

    for (int i = t; i < BC_ * 64; i += 256) {
        int ch = i >> 6, px = i & 63;
        float v = y2[(((size_t)n * BC_ + ch) << 12) + px0 + px];
        cfs[ch][px] = tanhf(v * scs[ch] + shs[ch]);
    }
    __syncthreads();

    int px = t & 63, cgrp = t >> 6;
    const float* Pb = P + (((size_t)n * PCH_) << 12) + px0 + px;
    float* Yb = Y + (((size_t)n * DDIM_) << 12) + px0 + px;
    for (int cc = 0; cc < 8; cc++) {
        int c = cgrp * 8 + cc;
        float pv[TB_];
        #pragma unroll
        for (int tt = 0; tt < TB_; tt++)
            pv[tt] = Pb[(size_t)(tt * C_ + c) << 12];
        #pragma unroll
        for (int m = 0; m < NB_; m++) {
            float a = 0.f;
            #pragma unroll
            for (int tt = 0; tt < TB_; tt++)
                a += cfs[m * TB_ + tt][px] * pv[tt];
            Yb[(size_t)(c * NB_ + m) << 12] = a;
        }
    }
}

// ---------------------------------------------------------------------------
// out[n][o][px] = out_b[o] + sum_d out_w[o][d]*Y[d][px]
// grid 512 = n(8) x pxblk(64); block 256 = 16 og(4 o) x 16 pxg(4 px)
__global__ __launch_bounds__(256) void k_proj(const float* __restrict__ Y,
                                              const float* __restrict__ out_w,
                                              const float* __restrict__ out_b,
                                              float* __restrict__ out) {
    __shared__ float swt[DDIM_][OUT_];
    int bid = blockIdx.x;
    int n = bid >> 6;
    int px0 = (bid & 63) << 6;
    int t = threadIdx.x;
    for (int i = t; i < DDIM_ * OUT_; i += 256) {
        int d = i >> 6, o = i & 63;
        swt[d][o] = out_w[o * DDIM_ + d];
    }
    __syncthreads();

    int pxg = t & 15, og = t >> 4;
    int px = px0 + pxg * 4;
    int o0 = og * 4;
    float acc[4][4];
    #pragma unroll
    for (int j = 0; j < 4; j++)
        #pragma unroll
        for (int i = 0; i < 4; i++) acc[j][i] = 0.f;

    const float* Yb = Y + (((size_t)n * DDIM_) << 12) + px;
    for (int d = 0; d < DDIM_; d++) {
        float4 yv = *(const float4*)(Yb + ((size_t)d << 12));
        float4 wv = *(const float4*)&swt[d][o0];
        float wr[4] = {wv.x, wv.y, wv.z, wv.w};
        #pragma unroll
        for (int j = 0; j < 4; j++) {
            acc[j][0] += wr[j] * yv.x; acc[j][1] += wr[j] * yv.y;
            acc[j][2] += wr[j] * yv.z; acc[j][3] += wr[j] * yv.w;
        }
    }
    #pragma unroll
    for (int j = 0; j < 4; j++) {
        int o = o0 + j;
        float bbv = out_b[o];
        float4 v = make_float4(acc[j][0] + bbv, acc[j][1] + bbv, acc[j][2] + bbv, acc[j][3] + bbv);
        *(float4*)(out + (((size_t)n * OUT_ + o) << 12) + px) = v;
    }
}

extern "C" void kernel_launch(void* const* d_in, const int* in_sizes, int n_in,
                              void* d_out, int out_size, void* d_ws, size_t ws_size,
                              hipStream_t stream) {
    const float* x       = (const float*)d_in[0];
    const float* conv1_w = (const float*)d_in[1];
    const float* conv1_b = (const float*)d_in[2];
    const float* bn1_g   = (const float*)d_in[3];
    const float* bn1_b   = (const float*)d_in[4];
    const float* conv2_w = (const float*)d_in[5];
    const float* conv2_b = (const float*)d_in[6];
    const float* bn2_g   = (const float*)d_in[7];
    const float* bn2_b   = (const float*)d_in[8];
    const float* bases   = (const float*)d_in[9];
    const float* out_w   = (const float*)d_in[10];
    const float* out_b   = (const float*)d_in[11];
    float* out = (float*)d_out;

    float* y1  = (float*)d_ws;                    // 2,097,152 f32
    float* y2  = y1 + (size_t)N_ * INTER_ * HW_;  // 3,538,944 f32
    float* P   = y2 + (size_t)N_ * BC_ * HW_;     // 18,874,368 f32
    float* Yt  = P  + (size_t)N_ * PCH_ * HW_;    // 6,291,456 f32
    float2* part1 = (float2*)(Yt + (size_t)N_ * DDIM_ * HW_);  // 64*8
    float2* part2 = part1 + INTER_ * 8;                        // 108*8

    // bf16 scratch aliases regions written later:
    unsigned short* xb  = (unsigned short*)P;       // consumed by conv1; P written at k_pconv
    unsigned short* y1b = xb + (size_t)NHW_ * C_;
    unsigned short* wb1 = (unsigned short*)Yt;      // consumed by convs; Yt written at k_y
    unsigned short* wb2 = wb1 + 9 * 64 * 32;

    k_prep<<<836, 256, 0, stream>>>(x, conv1_w, conv2_w, xb, wb1, wb2);

    k_conv_mfma<C_, 4><<<N_ * (H_ / 2), 256, 0, stream>>>(xb, wb1, conv1_b, y1, INTER_);
    k_bnpart<<<INTER_ * 8, 256, 0, stream>>>(y1, part1, INTER_);
    k_bntr<<<512, 256, 0, stream>>>(y1, part1, bn1_g, bn1_b, y1b);

    k_conv_mfma<INTER_, 7><<<N_ * (H_ / 2), 256, 0, stream>>>(y1b, wb2, conv2_b, y2, BC_);
    k_bnpart<<<BC_ * 8, 256, 0, stream>>>(y2, part2, BC_);

    k_pconv<<<N_ * C_ * 2, 256, 0, stream>>>(x, bases, P);
    k_y<<<512, 256, 0, stream>>>(y2, part2, bn2_g, bn2_b, P, Yt);
    k_proj<<<512, 256, 0, stream>>>(Yt, out_w, out_b, out);
}